// Round 12
// baseline (572.264 us; speedup 1.0000x reference)
//
#include <hip/hip_runtime.h>
#include <math.h>

#define N_NODES 50000
#define N_EDGES 500000
#define NPB 8       // nodes per conv block (50000 = 8 * 6250)
#define GROUPS 8    // 32-lane groups per 256-thread block

__device__ __forceinline__ float gelu_fast(float x) {
    const float k0 = 0.7978845608028654f;
    const float k1 = 0.044715f;
    float z2 = 2.f * k0 * (x + k1 * x * x * x);
    float ez = __expf(z2);
    float th = 1.f - 2.f * __builtin_amdgcn_rcpf(ez + 1.f);
    return 0.5f * x * (1.f + th);
}

__device__ __forceinline__ unsigned short f2bf(float x) {
    unsigned int u = __float_as_uint(x);
    unsigned int r = (u + 0x7FFFu + ((u >> 16) & 1u)) >> 16;  // RNE
    return (unsigned short)r;
}
__device__ __forceinline__ unsigned int pack2bf(float a, float b) {
    return (unsigned int)f2bf(a) | ((unsigned int)f2bf(b) << 16);
}
__device__ __forceinline__ float bf_lo(unsigned int w) {
    return __uint_as_float(w << 16);
}
__device__ __forceinline__ float bf_hi(unsigned int w) {
    return __uint_as_float(w & 0xffff0000u);
}

__device__ __forceinline__ void lds_add(float* p, float v) {
    unsigned int off = (unsigned int)(size_t)p;
    asm volatile("ds_add_f32 %0, %1" :: "v"(off), "v"(v) : "memory");
}

// K1: per-node lift.
__global__ void node_pre(const float* __restrict__ node_input,
                         const float* __restrict__ W1_s,
                         const float* __restrict__ W1_v,
                         float* __restrict__ feat,
                         float* __restrict__ out) {
    __shared__ float lWs[32 * 64];
    __shared__ float lWv[32 * 64];
    for (int i = threadIdx.x; i < 2048; i += blockDim.x) {
        lWs[i] = W1_s[i];
        lWv[i] = W1_v[i];
    }
    __syncthreads();
    int n = blockIdx.x * blockDim.x + threadIdx.x;
    if (n >= N_NODES) return;
    const float inv_sqrt_mul = 0.17677669529663687f;
    const float a_mix = 0.9219544457292887f;

    float s[32];
#pragma unroll
    for (int u = 0; u < 32; ++u) s[u] = node_input[n * 128 + u];
#pragma unroll 4
    for (int w = 0; w < 64; ++w) {
        float acc = 0.f;
#pragma unroll
        for (int u = 0; u < 32; ++u) acc += s[u] * lWs[u * 64 + w];
        acc *= inv_sqrt_mul;
        if (w < 32) feat[(size_t)n * 128 + w * 4 + 0] = acc;
        else        out[n * 128 + (w - 32)] = a_mix * acc;
    }
#pragma unroll
    for (int k = 0; k < 3; ++k) {
        float vk[32];
#pragma unroll
        for (int u = 0; u < 32; ++u) vk[u] = node_input[n * 128 + 32 + u * 3 + k];
#pragma unroll 4
        for (int w = 0; w < 64; ++w) {
            float acc = 0.f;
#pragma unroll
            for (int u = 0; u < 32; ++u) acc += vk[u] * lWv[u * 64 + w];
            acc *= inv_sqrt_mul;
            if (w < 32) feat[(size_t)n * 128 + w * 4 + 1 + k] = acc;
            else        out[n * 128 + 32 + (w - 32) * 3 + k] = a_mix * acc;
        }
    }
}

// K2a
__global__ void hist_kernel(const int* __restrict__ edge_dst, int* __restrict__ counts) {
    int e = blockIdx.x * blockDim.x + threadIdx.x;
    if (e < N_EDGES) atomicAdd(&counts[edge_dst[e]], 1);
}

// K2b
__global__ void scan_kernel(const int* __restrict__ counts,
                            int* __restrict__ offsets,
                            int* __restrict__ cursor) {
    const int T = 1024;
    __shared__ int partial[T];
    int t = threadIdx.x;
    const int chunk = (N_NODES + T - 1) / T;
    int start = t * chunk;
    int end = start + chunk; if (end > N_NODES) end = N_NODES;
    if (start > N_NODES) start = N_NODES;
    int sum = 0;
    for (int i = start; i < end; ++i) sum += counts[i];
    partial[t] = sum;
    __syncthreads();
    for (int off = 1; off < T; off <<= 1) {
        int other = (t >= off) ? partial[t - off] : 0;
        __syncthreads();
        partial[t] += other;
        __syncthreads();
    }
    int run = (t == 0) ? 0 : partial[t - 1];
    for (int i = start; i < end; ++i) {
        offsets[i] = run;
        cursor[i] = run;
        run += counts[i];
    }
    if (t == T - 1) offsets[N_NODES] = run;
}

// K2c: scatter metadata into dst-sorted order + record orig->sorted mapping.
__global__ void scatter_kernel(const int* __restrict__ edge_src,
                               const int* __restrict__ edge_dst,
                               const float* __restrict__ edge_attr,
                               int* __restrict__ cursor,
                               float4* __restrict__ ySorted,
                               int2* __restrict__ srcdst,
                               int* __restrict__ epos) {
    int e = blockIdx.x * blockDim.x + threadIdx.x;
    if (e >= N_EDGES) return;
    int d = edge_dst[e];
    int pos = atomicAdd(&cursor[d], 1);
    ySorted[pos] = *(const float4*)(edge_attr + (size_t)e * 4);
    srcdst[pos] = make_int2(edge_src[e], d);
    epos[e] = pos;
}

// K_h: layers 1+2. One thread per input-order edge (coalesced reads, SGPR
// weights); writes h (32 bf16, 64B) DIRECTLY to its dst-sorted slot —
// scattered stores are fire-and-forget, and conv then reads h sequentially.
__global__ void __launch_bounds__(256)
h_kernel(const float* __restrict__ edge_scalars,
         const int* __restrict__ epos,
         const float* __restrict__ M0,
         const float* __restrict__ M1,
         uint4* __restrict__ hSorted) {
    const int e = blockIdx.x * blockDim.x + threadIdx.x;
    if (e >= N_EDGES) return;

    const float inv_sqrt8  = 0.35355339059327373f;
    const float inv_sqrt32 = 0.17677669529663687f;

    const float4 s0 = *(const float4*)(edge_scalars + (size_t)e * 8);
    const float4 s1 = *(const float4*)(edge_scalars + (size_t)e * 8 + 4);
    const int pos = epos[e];

    float t[32];
#pragma unroll
    for (int u = 0; u < 32; ++u) {
        float acc = s0.x * M0[0 * 32 + u] + s0.y * M0[1 * 32 + u]
                  + s0.z * M0[2 * 32 + u] + s0.w * M0[3 * 32 + u]
                  + s1.x * M0[4 * 32 + u] + s1.y * M0[5 * 32 + u]
                  + s1.z * M0[6 * 32 + u] + s1.w * M0[7 * 32 + u];
        t[u] = gelu_fast(acc * inv_sqrt8);
    }
    float h[32];
#pragma unroll
    for (int u = 0; u < 32; ++u) {
        float acc = 0.f;
#pragma unroll
        for (int m = 0; m < 32; ++m) acc += t[m] * M1[m * 32 + u];
        h[u] = gelu_fast(acc * inv_sqrt32);
    }

    uint4* dst = hSorted + (size_t)pos * 4;
#pragma unroll
    for (int c = 0; c < 4; ++c) {
        uint4 pk;
        pk.x = pack2bf(h[c * 8 + 0], h[c * 8 + 1]);
        pk.y = pack2bf(h[c * 8 + 2], h[c * 8 + 3]);
        pk.z = pack2bf(h[c * 8 + 4], h[c * 8 + 5]);
        pk.w = pack2bf(h[c * 8 + 6], h[c * 8 + 7]);
        dst[c] = pk;
    }
}

// K_conv: block owns NPB contiguous dst nodes. Software-pipelined edge walk:
// srcdst kept 2 ahead, y/h/feat issued 1 ahead (feat addr from the resident
// next srcdst). h reads are sequential+uniform. Register run-combining;
// native ds_add_f32 into 8KB sacc; W2 epilogue.
__global__ void __launch_bounds__(256)
conv_kernel(const uint4* __restrict__ hSorted,
            const float4* __restrict__ ySorted,
            const int2* __restrict__ srcdst,
            const int* __restrict__ offsets,
            const float* __restrict__ Wtp0,
            const float* __restrict__ Wtp1,
            const float* __restrict__ Wtp2,
            const float* __restrict__ Wtp3,
            const float* __restrict__ W2_s,
            const float* __restrict__ W2_v,
            const float* __restrict__ feat,
            float* __restrict__ out) {
    __shared__ float sacc[NPB * 256];
    for (int i = threadIdx.x; i < NPB * 256; i += blockDim.x) sacc[i] = 0.f;

    const int lane = threadIdx.x & 31;
    const int g = threadIdx.x >> 5;

    // one-time per-lane Wtp columns (channel = lane), 1/sqrt(32) folded in
    const float inv_sqrt32 = 0.17677669529663687f;
    unsigned int wA[32], wB[32];
#pragma unroll
    for (int j = 0; j < 32; ++j) {
        wA[j] = pack2bf(Wtp0[j * 32 + lane] * inv_sqrt32,
                        Wtp1[j * 32 + lane] * inv_sqrt32);
        wB[j] = pack2bf(Wtp2[j * 32 + lane] * inv_sqrt32,
                        Wtp3[j * 32 + lane] * inv_sqrt32);
    }
    __syncthreads();

    const int n0 = blockIdx.x * NPB;
    const int eb = offsets[n0];
    const int ee = offsets[n0 + NPB];
    const float INV3 = 0.5773502691896258f;
    const float4* feat4 = (const float4*)feat;

    const int total = ee - eb;
    const int per = (total + GROUPS - 1) / GROUPS;
    const int es = eb + g * per;
    int et = es + per; if (et > ee) et = ee;

    float r0 = 0.f, r1 = 0.f, r2 = 0.f, r3 = 0.f;
    float r4 = 0.f, r5 = 0.f, r6 = 0.f, r7 = 0.f;
    int cur = -1;

    if (es < et) {
        const int last = et - 1;
        // prologue: e=es fully loaded; srcdst for es+1 resident
        int2 sd = srcdst[es];
        float4 yq = ySorted[es];
        uint4 h0 = hSorted[(size_t)es * 4 + 0];
        uint4 h1 = hSorted[(size_t)es * 4 + 1];
        uint4 h2 = hSorted[(size_t)es * 4 + 2];
        uint4 h3 = hSorted[(size_t)es * 4 + 3];
        float4 f = feat4[(size_t)sd.x * 32 + lane];
        int e1 = es + 1 <= last ? es + 1 : last;
        int2 sdN = srcdst[e1];

        for (int e = es; e < et; ++e) {
            // ---- issue prefetches: e+1 data (addr from resident sdN), e+2 srcdst
            const int ep1 = e + 1 <= last ? e + 1 : last;
            const int ep2 = e + 2 <= last ? e + 2 : last;
            float4 yqN = ySorted[ep1];
            uint4 h0N = hSorted[(size_t)ep1 * 4 + 0];
            uint4 h1N = hSorted[(size_t)ep1 * 4 + 1];
            uint4 h2N = hSorted[(size_t)ep1 * 4 + 2];
            uint4 h3N = hSorted[(size_t)ep1 * 4 + 3];
            float4 fN = feat4[(size_t)sdN.x * 32 + lane];
            int2 sdNN = srcdst[ep2];

            // ---- flush on dst change
            if (sd.y != cur) {
                if (cur >= 0) {
                    float* ap = sacc + (cur - n0) * 256;
                    lds_add(ap + lane, r0);
                    lds_add(ap + 32 + lane, r1);
                    lds_add(ap + 64 + lane * 3 + 0, r2);
                    lds_add(ap + 64 + lane * 3 + 1, r3);
                    lds_add(ap + 64 + lane * 3 + 2, r4);
                    lds_add(ap + 160 + lane * 3 + 0, r5);
                    lds_add(ap + 160 + lane * 3 + 1, r6);
                    lds_add(ap + 160 + lane * 3 + 2, r7);
                }
                cur = sd.y;
                r0 = r1 = r2 = r3 = r4 = r5 = r6 = r7 = 0.f;
            }

            // ---- layer 3 for this lane's channel u=lane
            float w0 = 0.f, w1 = 0.f, w2 = 0.f, w3 = 0.f;
            const unsigned int hw[16] = {h0.x, h0.y, h0.z, h0.w,
                                         h1.x, h1.y, h1.z, h1.w,
                                         h2.x, h2.y, h2.z, h2.w,
                                         h3.x, h3.y, h3.z, h3.w};
#pragma unroll
            for (int k = 0; k < 16; ++k) {
                const float hlo = bf_lo(hw[k]);
                const float hhi = bf_hi(hw[k]);
                const unsigned int a0 = wA[2 * k],     b0 = wB[2 * k];
                const unsigned int a1 = wA[2 * k + 1], b1 = wB[2 * k + 1];
                w0 += hlo * bf_lo(a0); w1 += hlo * bf_hi(a0);
                w2 += hlo * bf_lo(b0); w3 += hlo * bf_hi(b0);
                w0 += hhi * bf_lo(a1); w1 += hhi * bf_hi(a1);
                w2 += hhi * bf_lo(b1); w3 += hhi * bf_hi(b1);
            }

            const float dvy = f.y * yq.y + f.z * yq.z + f.w * yq.w;
            const float w1es = w1 * f.x;
            const float w2y0 = w2 * yq.x;

            r0 += w0 * f.x * yq.x;
            r1 += w3 * dvy * INV3;
            r2 += w1es * yq.y;
            r3 += w1es * yq.z;
            r4 += w1es * yq.w;
            r5 += w2y0 * f.y;
            r6 += w2y0 * f.z;
            r7 += w2y0 * f.w;

            // ---- rotate
            sd = sdN; sdN = sdNN;
            yq = yqN; h0 = h0N; h1 = h1N; h2 = h2N; h3 = h3N; f = fN;
        }
        if (cur >= 0) {
            float* ap = sacc + (cur - n0) * 256;
            lds_add(ap + lane, r0);
            lds_add(ap + 32 + lane, r1);
            lds_add(ap + 64 + lane * 3 + 0, r2);
            lds_add(ap + 64 + lane * 3 + 1, r3);
            lds_add(ap + 64 + lane * 3 + 2, r4);
            lds_add(ap + 160 + lane * 3 + 0, r5);
            lds_add(ap + 160 + lane * 3 + 1, r6);
            lds_add(ap + 160 + lane * 3 + 2, r7);
        }
    }
    asm volatile("s_waitcnt lgkmcnt(0)" ::: "memory");
    __syncthreads();

    // epilogue: 1 node per group (NPB == GROUPS)
    const float scale = 0.31622776601683794f * 0.125f * 0.3872983346207417f;
    {
        const int li = g;
        const float* ap = sacc + li * 256;
        float cs = 0.f, cv0 = 0.f, cv1 = 0.f, cv2 = 0.f;
#pragma unroll 8
        for (int j = 0; j < 64; ++j) {
            const float as = ap[j];
            cs += as * __ldg(&W2_s[j * 32 + lane]);
            const float wv = __ldg(&W2_v[j * 32 + lane]);
            cv0 += ap[64 + 3 * j + 0] * wv;
            cv1 += ap[64 + 3 * j + 1] * wv;
            cv2 += ap[64 + 3 * j + 2] * wv;
        }
        float* o = out + (size_t)(n0 + li) * 128;
        o[lane]              += scale * cs;
        o[32 + lane * 3 + 0] += scale * cv0;
        o[32 + lane * 3 + 1] += scale * cv1;
        o[32 + lane * 3 + 2] += scale * cv2;
    }
}

extern "C" void kernel_launch(void* const* d_in, const int* in_sizes, int n_in,
                              void* d_out, int out_size, void* d_ws, size_t ws_size,
                              hipStream_t stream) {
    const float* node_input   = (const float*)d_in[0];
    const float* edge_attr    = (const float*)d_in[1];
    const float* edge_scalars = (const float*)d_in[2];
    const float* W1_s = (const float*)d_in[3];
    const float* W1_v = (const float*)d_in[4];
    const float* M0   = (const float*)d_in[5];
    const float* M1   = (const float*)d_in[6];
    const float* Wtp0 = (const float*)d_in[7];
    const float* Wtp1 = (const float*)d_in[8];
    const float* Wtp2 = (const float*)d_in[9];
    const float* Wtp3 = (const float*)d_in[10];
    const float* W2_s = (const float*)d_in[11];
    const float* W2_v = (const float*)d_in[12];
    const int* edge_src = (const int*)d_in[13];
    const int* edge_dst = (const int*)d_in[14];
    float* out = (float*)d_out;
    float* ws  = (float*)d_ws;

    float*  feat    = ws;                                           // N*128 (25.6 MB)
    float4* ySorted = (float4*)(feat + (size_t)N_NODES * 128);      // E float4 (8 MB)
    uint4*  hSorted = (uint4*)(ySorted + N_EDGES);                  // E*4 uint4 (32 MB)
    int2*   srcdst  = (int2*)(hSorted + (size_t)N_EDGES * 4);       // E int2 (4 MB)
    int*    epos    = (int*)(srcdst + N_EDGES);                     // E (2 MB)
    int*    counts  = epos + N_EDGES;                               // N
    int*    offsets = counts + N_NODES;                             // N+1
    int*    cursor  = offsets + N_NODES + 1;                        // N
    // total ~72 MB

    hipMemsetAsync(counts, 0, N_NODES * sizeof(int), stream);

    node_pre<<<(N_NODES + 255) / 256, 256, 0, stream>>>(node_input, W1_s, W1_v,
                                                        feat, out);

    hist_kernel<<<(N_EDGES + 255) / 256, 256, 0, stream>>>(edge_dst, counts);
    scan_kernel<<<1, 1024, 0, stream>>>(counts, offsets, cursor);
    scatter_kernel<<<(N_EDGES + 255) / 256, 256, 0, stream>>>(edge_src, edge_dst,
                                                              edge_attr, cursor,
                                                              ySorted, srcdst, epos);

    h_kernel<<<(N_EDGES + 255) / 256, 256, 0, stream>>>(edge_scalars, epos,
                                                        M0, M1, hSorted);

    conv_kernel<<<N_NODES / NPB, 256, 0, stream>>>(hSorted, ySorted, srcdst, offsets,
                                                   Wtp0, Wtp1, Wtp2, Wtp3,
                                                   W2_s, W2_v, feat, out);
}

// Round 13
// 555.984 us; speedup vs baseline: 1.0293x; 1.0293x over previous
//
#include <hip/hip_runtime.h>
#include <math.h>

#define N_NODES 50000
#define N_EDGES 500000
#define NPB 8       // nodes per conv block (50000 = 8 * 6250)
#define GROUPS 8    // 32-lane groups per 256-thread block

__device__ __forceinline__ float gelu_fast(float x) {
    const float k0 = 0.7978845608028654f;
    const float k1 = 0.044715f;
    float z2 = 2.f * k0 * (x + k1 * x * x * x);
    float ez = __expf(z2);
    float th = 1.f - 2.f * __builtin_amdgcn_rcpf(ez + 1.f);
    return 0.5f * x * (1.f + th);
}

__device__ __forceinline__ unsigned short f2bf(float x) {
    unsigned int u = __float_as_uint(x);
    unsigned int r = (u + 0x7FFFu + ((u >> 16) & 1u)) >> 16;  // RNE
    return (unsigned short)r;
}
__device__ __forceinline__ unsigned int pack2bf(float a, float b) {
    return (unsigned int)f2bf(a) | ((unsigned int)f2bf(b) << 16);
}
__device__ __forceinline__ float bf_lo(unsigned int w) {
    return __uint_as_float(w << 16);
}
__device__ __forceinline__ float bf_hi(unsigned int w) {
    return __uint_as_float(w & 0xffff0000u);
}

__device__ __forceinline__ void lds_add(float* p, float v) {
    unsigned int off = (unsigned int)(size_t)p;
    asm volatile("ds_add_f32 %0, %1" :: "v"(off), "v"(v) : "memory");
}

// K1: per-node lift.
__global__ void node_pre(const float* __restrict__ node_input,
                         const float* __restrict__ W1_s,
                         const float* __restrict__ W1_v,
                         float* __restrict__ feat,
                         float* __restrict__ out) {
    __shared__ float lWs[32 * 64];
    __shared__ float lWv[32 * 64];
    for (int i = threadIdx.x; i < 2048; i += blockDim.x) {
        lWs[i] = W1_s[i];
        lWv[i] = W1_v[i];
    }
    __syncthreads();
    int n = blockIdx.x * blockDim.x + threadIdx.x;
    if (n >= N_NODES) return;
    const float inv_sqrt_mul = 0.17677669529663687f;
    const float a_mix = 0.9219544457292887f;

    float s[32];
#pragma unroll
    for (int u = 0; u < 32; ++u) s[u] = node_input[n * 128 + u];
#pragma unroll 4
    for (int w = 0; w < 64; ++w) {
        float acc = 0.f;
#pragma unroll
        for (int u = 0; u < 32; ++u) acc += s[u] * lWs[u * 64 + w];
        acc *= inv_sqrt_mul;
        if (w < 32) feat[(size_t)n * 128 + w * 4 + 0] = acc;
        else        out[n * 128 + (w - 32)] = a_mix * acc;
    }
#pragma unroll
    for (int k = 0; k < 3; ++k) {
        float vk[32];
#pragma unroll
        for (int u = 0; u < 32; ++u) vk[u] = node_input[n * 128 + 32 + u * 3 + k];
#pragma unroll 4
        for (int w = 0; w < 64; ++w) {
            float acc = 0.f;
#pragma unroll
            for (int u = 0; u < 32; ++u) acc += vk[u] * lWv[u * 64 + w];
            acc *= inv_sqrt_mul;
            if (w < 32) feat[(size_t)n * 128 + w * 4 + 1 + k] = acc;
            else        out[n * 128 + 32 + (w - 32) * 3 + k] = a_mix * acc;
        }
    }
}

// K2a
__global__ void hist_kernel(const int* __restrict__ edge_dst, int* __restrict__ counts) {
    int e = blockIdx.x * blockDim.x + threadIdx.x;
    if (e < N_EDGES) atomicAdd(&counts[edge_dst[e]], 1);
}

// K2b
__global__ void scan_kernel(const int* __restrict__ counts,
                            int* __restrict__ offsets,
                            int* __restrict__ cursor) {
    const int T = 1024;
    __shared__ int partial[T];
    int t = threadIdx.x;
    const int chunk = (N_NODES + T - 1) / T;
    int start = t * chunk;
    int end = start + chunk; if (end > N_NODES) end = N_NODES;
    if (start > N_NODES) start = N_NODES;
    int sum = 0;
    for (int i = start; i < end; ++i) sum += counts[i];
    partial[t] = sum;
    __syncthreads();
    for (int off = 1; off < T; off <<= 1) {
        int other = (t >= off) ? partial[t - off] : 0;
        __syncthreads();
        partial[t] += other;
        __syncthreads();
    }
    int run = (t == 0) ? 0 : partial[t - 1];
    for (int i = start; i < end; ++i) {
        offsets[i] = run;
        cursor[i] = run;
        run += counts[i];
    }
    if (t == T - 1) offsets[N_NODES] = run;
}

// K2c: scatter metadata into dst-sorted order + record orig->sorted mapping.
__global__ void scatter_kernel(const int* __restrict__ edge_src,
                               const int* __restrict__ edge_dst,
                               const float* __restrict__ edge_attr,
                               int* __restrict__ cursor,
                               float4* __restrict__ ySorted,
                               int2* __restrict__ srcdst,
                               int* __restrict__ epos) {
    int e = blockIdx.x * blockDim.x + threadIdx.x;
    if (e >= N_EDGES) return;
    int d = edge_dst[e];
    int pos = atomicAdd(&cursor[d], 1);
    ySorted[pos] = *(const float4*)(edge_attr + (size_t)e * 4);
    srcdst[pos] = make_int2(edge_src[e], d);
    epos[e] = pos;
}

// K_h: layers 1+2. One thread per input-order edge (coalesced reads, SGPR
// weights); writes h (32 bf16, 64B) directly to its dst-sorted slot.
__global__ void __launch_bounds__(256)
h_kernel(const float* __restrict__ edge_scalars,
         const int* __restrict__ epos,
         const float* __restrict__ M0,
         const float* __restrict__ M1,
         uint4* __restrict__ hSorted) {
    const int e = blockIdx.x * blockDim.x + threadIdx.x;
    if (e >= N_EDGES) return;

    const float inv_sqrt8  = 0.35355339059327373f;
    const float inv_sqrt32 = 0.17677669529663687f;

    const float4 s0 = *(const float4*)(edge_scalars + (size_t)e * 8);
    const float4 s1 = *(const float4*)(edge_scalars + (size_t)e * 8 + 4);
    const int pos = epos[e];

    float t[32];
#pragma unroll
    for (int u = 0; u < 32; ++u) {
        float acc = s0.x * M0[0 * 32 + u] + s0.y * M0[1 * 32 + u]
                  + s0.z * M0[2 * 32 + u] + s0.w * M0[3 * 32 + u]
                  + s1.x * M0[4 * 32 + u] + s1.y * M0[5 * 32 + u]
                  + s1.z * M0[6 * 32 + u] + s1.w * M0[7 * 32 + u];
        t[u] = gelu_fast(acc * inv_sqrt8);
    }
    float h[32];
#pragma unroll
    for (int u = 0; u < 32; ++u) {
        float acc = 0.f;
#pragma unroll
        for (int m = 0; m < 32; ++m) acc += t[m] * M1[m * 32 + u];
        h[u] = gelu_fast(acc * inv_sqrt32);
    }

    uint4* dst = hSorted + (size_t)pos * 4;
#pragma unroll
    for (int c = 0; c < 4; ++c) {
        uint4 pk;
        pk.x = pack2bf(h[c * 8 + 0], h[c * 8 + 1]);
        pk.y = pack2bf(h[c * 8 + 2], h[c * 8 + 3]);
        pk.z = pack2bf(h[c * 8 + 4], h[c * 8 + 5]);
        pk.w = pack2bf(h[c * 8 + 6], h[c * 8 + 7]);
        dst[c] = pk;
    }
}

// K_conv: block owns NPB contiguous dst nodes. Wtp weights in LDS (uint4
// [k][lane], conflict-free ds_read_b128) -> minimal VGPRs, no per-block
// register weight fill; occupancy does the latency hiding. Register
// run-combining; native ds_add_f32 into 8KB sacc; W2 epilogue.
__global__ void __launch_bounds__(256, 6)
conv_kernel(const uint4* __restrict__ hSorted,
            const float4* __restrict__ ySorted,
            const int2* __restrict__ srcdst,
            const int* __restrict__ offsets,
            const float* __restrict__ Wtp0,
            const float* __restrict__ Wtp1,
            const float* __restrict__ Wtp2,
            const float* __restrict__ Wtp3,
            const float* __restrict__ W2_s,
            const float* __restrict__ W2_v,
            const float* __restrict__ feat,
            float* __restrict__ out) {
    __shared__ float sacc[NPB * 256];   // 8 KB
    __shared__ uint4 lW[16 * 32];       // 8 KB: [k][lane] packed bf16 Wtp

    for (int i = threadIdx.x; i < NPB * 256; i += blockDim.x) sacc[i] = 0.f;

    const float inv_sqrt32 = 0.17677669529663687f;
    // cooperative packed-weight fill: entry (k,ln) covers j = 2k, 2k+1; chan ln
    for (int idx = threadIdx.x; idx < 512; idx += blockDim.x) {
        const int k = idx >> 5, ln = idx & 31;
        const int j0 = 2 * k, j1 = 2 * k + 1;
        uint4 w;
        w.x = pack2bf(Wtp0[j0 * 32 + ln] * inv_sqrt32, Wtp1[j0 * 32 + ln] * inv_sqrt32);
        w.y = pack2bf(Wtp2[j0 * 32 + ln] * inv_sqrt32, Wtp3[j0 * 32 + ln] * inv_sqrt32);
        w.z = pack2bf(Wtp0[j1 * 32 + ln] * inv_sqrt32, Wtp1[j1 * 32 + ln] * inv_sqrt32);
        w.w = pack2bf(Wtp2[j1 * 32 + ln] * inv_sqrt32, Wtp3[j1 * 32 + ln] * inv_sqrt32);
        lW[idx] = w;
    }
    __syncthreads();

    const int lane = threadIdx.x & 31;
    const int g = threadIdx.x >> 5;
    const int n0 = blockIdx.x * NPB;
    const int eb = offsets[n0];
    const int ee = offsets[n0 + NPB];
    const float INV3 = 0.5773502691896258f;
    const float4* feat4 = (const float4*)feat;

    const int total = ee - eb;
    const int per = (total + GROUPS - 1) / GROUPS;
    const int es = eb + g * per;
    int et = es + per; if (et > ee) et = ee;

    float r0 = 0.f, r1 = 0.f, r2 = 0.f, r3 = 0.f;
    float r4 = 0.f, r5 = 0.f, r6 = 0.f, r7 = 0.f;
    int cur = -1;

    for (int e = es; e < et; ++e) {
        const int2 sd = srcdst[e];
        const float4 yq = ySorted[e];                    // uniform per group
        const uint4 h0 = hSorted[(size_t)e * 4 + 0];     // sequential + uniform
        const uint4 h1 = hSorted[(size_t)e * 4 + 1];
        const uint4 h2 = hSorted[(size_t)e * 4 + 2];
        const uint4 h3 = hSorted[(size_t)e * 4 + 3];
        const float4 f = feat4[(size_t)sd.x * 32 + lane];

        if (sd.y != cur) {
            if (cur >= 0) {
                float* ap = sacc + (cur - n0) * 256;
                lds_add(ap + lane, r0);
                lds_add(ap + 32 + lane, r1);
                lds_add(ap + 64 + lane * 3 + 0, r2);
                lds_add(ap + 64 + lane * 3 + 1, r3);
                lds_add(ap + 64 + lane * 3 + 2, r4);
                lds_add(ap + 160 + lane * 3 + 0, r5);
                lds_add(ap + 160 + lane * 3 + 1, r6);
                lds_add(ap + 160 + lane * 3 + 2, r7);
            }
            cur = sd.y;
            r0 = r1 = r2 = r3 = r4 = r5 = r6 = r7 = 0.f;
        }

        // layer 3 for this lane's channel u=lane: weights from LDS
        float w0 = 0.f, w1 = 0.f, w2 = 0.f, w3 = 0.f;
        const unsigned int hw[16] = {h0.x, h0.y, h0.z, h0.w,
                                     h1.x, h1.y, h1.z, h1.w,
                                     h2.x, h2.y, h2.z, h2.w,
                                     h3.x, h3.y, h3.z, h3.w};
#pragma unroll
        for (int k = 0; k < 16; ++k) {
            const uint4 wk = lW[k * 32 + lane];
            const float hlo = bf_lo(hw[k]);
            const float hhi = bf_hi(hw[k]);
            w0 += hlo * bf_lo(wk.x); w1 += hlo * bf_hi(wk.x);
            w2 += hlo * bf_lo(wk.y); w3 += hlo * bf_hi(wk.y);
            w0 += hhi * bf_lo(wk.z); w1 += hhi * bf_hi(wk.z);
            w2 += hhi * bf_lo(wk.w); w3 += hhi * bf_hi(wk.w);
        }

        const float dvy = f.y * yq.y + f.z * yq.z + f.w * yq.w;
        const float w1es = w1 * f.x;
        const float w2y0 = w2 * yq.x;

        r0 += w0 * f.x * yq.x;
        r1 += w3 * dvy * INV3;
        r2 += w1es * yq.y;
        r3 += w1es * yq.z;
        r4 += w1es * yq.w;
        r5 += w2y0 * f.y;
        r6 += w2y0 * f.z;
        r7 += w2y0 * f.w;
    }
    if (cur >= 0) {
        float* ap = sacc + (cur - n0) * 256;
        lds_add(ap + lane, r0);
        lds_add(ap + 32 + lane, r1);
        lds_add(ap + 64 + lane * 3 + 0, r2);
        lds_add(ap + 64 + lane * 3 + 1, r3);
        lds_add(ap + 64 + lane * 3 + 2, r4);
        lds_add(ap + 160 + lane * 3 + 0, r5);
        lds_add(ap + 160 + lane * 3 + 1, r6);
        lds_add(ap + 160 + lane * 3 + 2, r7);
    }
    asm volatile("s_waitcnt lgkmcnt(0)" ::: "memory");
    __syncthreads();

    // epilogue: 1 node per group (NPB == GROUPS)
    const float scale = 0.31622776601683794f * 0.125f * 0.3872983346207417f;
    {
        const int li = g;
        const float* ap = sacc + li * 256;
        float cs = 0.f, cv0 = 0.f, cv1 = 0.f, cv2 = 0.f;
#pragma unroll 8
        for (int j = 0; j < 64; ++j) {
            const float as = ap[j];
            cs += as * __ldg(&W2_s[j * 32 + lane]);
            const float wv = __ldg(&W2_v[j * 32 + lane]);
            cv0 += ap[64 + 3 * j + 0] * wv;
            cv1 += ap[64 + 3 * j + 1] * wv;
            cv2 += ap[64 + 3 * j + 2] * wv;
        }
        float* o = out + (size_t)(n0 + li) * 128;
        o[lane]              += scale * cs;
        o[32 + lane * 3 + 0] += scale * cv0;
        o[32 + lane * 3 + 1] += scale * cv1;
        o[32 + lane * 3 + 2] += scale * cv2;
    }
}

extern "C" void kernel_launch(void* const* d_in, const int* in_sizes, int n_in,
                              void* d_out, int out_size, void* d_ws, size_t ws_size,
                              hipStream_t stream) {
    const float* node_input   = (const float*)d_in[0];
    const float* edge_attr    = (const float*)d_in[1];
    const float* edge_scalars = (const float*)d_in[2];
    const float* W1_s = (const float*)d_in[3];
    const float* W1_v = (const float*)d_in[4];
    const float* M0   = (const float*)d_in[5];
    const float* M1   = (const float*)d_in[6];
    const float* Wtp0 = (const float*)d_in[7];
    const float* Wtp1 = (const float*)d_in[8];
    const float* Wtp2 = (const float*)d_in[9];
    const float* Wtp3 = (const float*)d_in[10];
    const float* W2_s = (const float*)d_in[11];
    const float* W2_v = (const float*)d_in[12];
    const int* edge_src = (const int*)d_in[13];
    const int* edge_dst = (const int*)d_in[14];
    float* out = (float*)d_out;
    float* ws  = (float*)d_ws;

    float*  feat    = ws;                                           // N*128 (25.6 MB)
    float4* ySorted = (float4*)(feat + (size_t)N_NODES * 128);      // E float4 (8 MB)
    uint4*  hSorted = (uint4*)(ySorted + N_EDGES);                  // E*4 uint4 (32 MB)
    int2*   srcdst  = (int2*)(hSorted + (size_t)N_EDGES * 4);       // E int2 (4 MB)
    int*    epos    = (int*)(srcdst + N_EDGES);                     // E (2 MB)
    int*    counts  = epos + N_EDGES;                               // N
    int*    offsets = counts + N_NODES;                             // N+1
    int*    cursor  = offsets + N_NODES + 1;                        // N
    // total ~72 MB

    hipMemsetAsync(counts, 0, N_NODES * sizeof(int), stream);

    node_pre<<<(N_NODES + 255) / 256, 256, 0, stream>>>(node_input, W1_s, W1_v,
                                                        feat, out);

    hist_kernel<<<(N_EDGES + 255) / 256, 256, 0, stream>>>(edge_dst, counts);
    scan_kernel<<<1, 1024, 0, stream>>>(counts, offsets, cursor);
    scatter_kernel<<<(N_EDGES + 255) / 256, 256, 0, stream>>>(edge_src, edge_dst,
                                                              edge_attr, cursor,
                                                              ySorted, srcdst, epos);

    h_kernel<<<(N_EDGES + 255) / 256, 256, 0, stream>>>(edge_scalars, epos,
                                                        M0, M1, hSorted);

    conv_kernel<<<N_NODES / NPB, 256, 0, stream>>>(hSorted, ySorted, srcdst, offsets,
                                                   Wtp0, Wtp1, Wtp2, Wtp3,
                                                   W2_s, W2_v, feat, out);
}